// Round 5
// baseline (58.070 us; speedup 1.0000x reference)
//
#include <hip/hip_runtime.h>
#include <hip/hip_bf16.h>

// Problem constants
constexpr int B = 48, J = 17, H = 128, W = 128, P = 30;
constexpr int HW = H * W;                   // 16384
constexpr int NPLANES = B * J;              // 816
constexpr int SUBS = 4;                     // chunks per plane
constexpr int CHUNK_FLOATS = HW / SUBS;     // 4096
constexpr int NCHUNK = NPLANES * SUBS;      // 3264
constexpr int AE_BLOCKS = B;                // 48
// Grid: block 0 = watcher/finalize, blocks 1..48 = AE, blocks 49..3312 = MSE chunks.
// ws layout: [0:4) u32 ticket (memset to 0 each replay); byte 16.. : u64 partials[NCHUNK]
//   partial = bitcast(float2{sq_partial, gtsum_partial}), written write-through (agent scope).

union PackF2 { unsigned long long u; float2 f; };

__global__ __launch_bounds__(256) void fused_kernel(
        const float* __restrict__ outputs,
        const float* __restrict__ heatmaps,
        const unsigned* __restrict__ joints_u32,
        unsigned* __restrict__ ticket,
        unsigned long long* __restrict__ parts,
        float* __restrict__ out) {
    int t = threadIdx.x;

    if (blockIdx.x == 0) {
        // ---- watcher / finalize ----
        if (t == 0) {
            while (__hip_atomic_load(ticket, __ATOMIC_RELAXED,
                                     __HIP_MEMORY_SCOPE_AGENT) != (unsigned)NCHUNK) {
                __builtin_amdgcn_s_sleep(8);
            }
            // one acquire to order the partial reads after the spin exit
            (void)__hip_atomic_load(ticket, __ATOMIC_ACQUIRE, __HIP_MEMORY_SCOPE_AGENT);
        }
        __syncthreads();

        float s = 0.f, c = 0.f;
        for (int p = t; p < NPLANES; p += 256) {
            float sq = 0.f, gs = 0.f;
#pragma unroll
            for (int sub = 0; sub < SUBS; ++sub) {
                PackF2 pk;
                pk.u = __hip_atomic_load(parts + p * SUBS + sub, __ATOMIC_RELAXED,
                                         __HIP_MEMORY_SCOPE_AGENT);
                sq += pk.f.x; gs += pk.f.y;
            }
            if (gs > 0.f) { s += sq * (1.f / HW); c += 1.f; }
        }
        for (int off = 32; off > 0; off >>= 1) {
            s += __shfl_xor(s, off);
            c += __shfl_xor(c, off);
        }
        __shared__ float s_s[4], s_c[4];
        int wave = t >> 6;
        if ((t & 63) == 0) { s_s[wave] = s; s_c[wave] = c; }
        __syncthreads();
        if (t == 0) {
            out[0] = (s_s[0] + s_s[1] + s_s[2] + s_s[3]) /
                     (s_c[0] + s_c[1] + s_c[2] + s_c[3]);
        }
        return;
    }

    if (blockIdx.x > AE_BLOCKS) {
        // ---- MSE quarter-plane chunk ----
        int chunk = blockIdx.x - 1 - AE_BLOCKS;     // 0..3263
        int plane = chunk >> 2, sub = chunk & 3;
        int b = plane / J, j = plane % J;
        const float4* pred = reinterpret_cast<const float4*>(
            outputs + ((size_t)b * 2 * J + j) * HW + sub * CHUNK_FLOATS);
        const float4* gt = reinterpret_cast<const float4*>(
            heatmaps + (size_t)plane * HW + sub * CHUNK_FLOATS);

        float sq = 0.f, gs = 0.f;
#pragma unroll
        for (int k = 0; k < CHUNK_FLOATS / 4 / 256; ++k) {   // 4 iters
            float4 p = pred[t + k * 256];
            float4 g = gt[t + k * 256];
            float d0 = p.x - g.x, d1 = p.y - g.y, d2 = p.z - g.z, d3 = p.w - g.w;
            sq += d0 * d0 + d1 * d1 + d2 * d2 + d3 * d3;
            gs += g.x + g.y + g.z + g.w;
        }
        for (int off = 32; off > 0; off >>= 1) {
            sq += __shfl_xor(sq, off);
            gs += __shfl_xor(gs, off);
        }
        __shared__ float s_sq[4], s_gs[4];
        int wave = t >> 6;
        if ((t & 63) == 0) { s_sq[wave] = sq; s_gs[wave] = gs; }
        __syncthreads();
        if (t == 0) {
            PackF2 pk;
            pk.f = make_float2(s_sq[0] + s_sq[1] + s_sq[2] + s_sq[3],
                               s_gs[0] + s_gs[1] + s_gs[2] + s_gs[3]);
            // write-through to coherent point (no dirty L2 line, no fence needed)
            __hip_atomic_store(parts + chunk, pk.u, __ATOMIC_RELAXED,
                               __HIP_MEMORY_SCOPE_AGENT);
            // wave-local: ensure the store completed before the ticket bump
            asm volatile("s_waitcnt vmcnt(0)" ::: "memory");
            __hip_atomic_fetch_add(ticket, 1u, __ATOMIC_RELAXED,
                                   __HIP_MEMORY_SCOPE_AGENT);
        }
        return;
    }

    // ---- AE for batch b (blocks 1..48) ----
    int b = blockIdx.x - 1;
    const float* tags = outputs + ((size_t)b * 2 * J + J) * HW;

    // dtype probe on this batch's joints region (int64-assumed layout):
    // P*J*2 = 1020 int64 values -> odd u32 words all zero iff int64.
    const unsigned* jw = joints_u32 + (size_t)b * P * J * 2 * 2;
    unsigned ob = 0;
#pragma unroll
    for (int k = 0; k < 4; ++k) {
        int i = t + k * 256;
        if (i < P * J * 2) ob |= jw[2 * i + 1];
    }
    __shared__ unsigned s_ob[4];
    for (int off = 32; off > 0; off >>= 1) ob |= (unsigned)__shfl_xor((int)ob, off);
    int wv = t >> 6;
    if ((t & 63) == 0) s_ob[wv] = ob;
    __shared__ float m_sh[P];
    __shared__ int v_sh[P];
    __syncthreads();
    bool is64 = (s_ob[0] | s_ob[1] | s_ob[2] | s_ob[3]) == 0u;

    if (t >= 64) return;
    int lane = t;

    float per_pull = 0.f, m = 0.f;
    int validp = 0;

    if (lane < P) {
        float tv[J];
        int   vv[J];
        int cnt = 0;
        float sum = 0.f;
        if (is64) {
            const long long* jp = reinterpret_cast<const long long*>(joints_u32)
                                  + ((size_t)b * P + lane) * J * 2;
#pragma unroll
            for (int j = 0; j < J; ++j) {
                int idx = (int)jp[2 * j];
                int vis = jp[2 * j + 1] > 0;
                float tval = tags[idx];
                tv[j] = tval; vv[j] = vis;
                cnt += vis;
                sum += vis ? tval : 0.f;
            }
        } else {
            const int* jp = reinterpret_cast<const int*>(joints_u32)
                            + ((size_t)b * P + lane) * J * 2;
#pragma unroll
            for (int j = 0; j < J; ++j) {
                int idx = jp[2 * j];
                int vis = jp[2 * j + 1] > 0;
                float tval = tags[idx];
                tv[j] = tval; vv[j] = vis;
                cnt += vis;
                sum += vis ? tval : 0.f;
            }
        }
        float safe = cnt > 0 ? (float)cnt : 1.f;
        m = sum / safe;
        float pp = 0.f;
#pragma unroll
        for (int j = 0; j < J; ++j) {
            float d = tv[j] - m;
            pp += vv[j] ? d * d : 0.f;
        }
        validp = (cnt > 0) ? 1 : 0;
        per_pull = validp ? pp / safe : 0.f;
        m_sh[lane] = m;
        v_sh[lane] = validp;
    }
    // single wave: drain LDS writes so all lanes see m_sh/v_sh
    __builtin_amdgcn_s_waitcnt(0);

    float push_p = 0.f;
    if (lane < P && validp) {
#pragma unroll
        for (int k = 0; k < P; ++k) {
            if (v_sh[k]) {
                float d = m - m_sh[k];
                push_p += __expf(-d * d);
            }
        }
    }

    float v0 = per_pull, v1 = push_p, v2 = (float)validp;
    for (int off = 32; off > 0; off >>= 1) {
        v0 += __shfl_xor(v0, off);
        v1 += __shfl_xor(v1, off);
        v2 += __shfl_xor(v2, off);
    }
    if (lane == 0) {
        float num_tags = v2;
        float pull = v0 / fmaxf(num_tags, 1.f);
        float push_raw = v1 - num_tags;
        float denom = (num_tags - 1.f) * num_tags;
        float push = (num_tags >= 2.f) ? (push_raw / (denom > 0.f ? denom : 1.f)) * 0.5f : 0.f;
        out[1 + b] = push;
        out[1 + B + b] = pull;
    }
}

extern "C" void kernel_launch(void* const* d_in, const int* in_sizes, int n_in,
                              void* d_out, int out_size, void* d_ws, size_t ws_size,
                              hipStream_t stream) {
    const float* outputs  = (const float*)d_in[0];
    const float* heatmaps = (const float*)d_in[1];
    const unsigned* joints = (const unsigned*)d_in[2];
    float* out = (float*)d_out;
    unsigned* ticket = (unsigned*)d_ws;
    unsigned long long* parts =
        reinterpret_cast<unsigned long long*>((char*)d_ws + 16);

    hipMemsetAsync(d_ws, 0, 4, stream);   // zero ticket each replay
    fused_kernel<<<1 + AE_BLOCKS + NCHUNK, 256, 0, stream>>>(
        outputs, heatmaps, joints, ticket, parts, out);
}

// Round 6
// 55.431 us; speedup vs baseline: 1.0476x; 1.0476x over previous
//
#include <hip/hip_runtime.h>
#include <hip/hip_bf16.h>

// Problem constants
constexpr int B = 48, J = 17, H = 128, W = 128, P = 30;
constexpr int HW = H * W;                   // 16384
constexpr int NPLANES = B * J;              // 816
constexpr int SUBS = 4;                     // chunks per plane
constexpr int CHUNK_FLOATS = HW / SUBS;     // 4096
constexpr int NCHUNK = NPLANES * SUBS;      // 3264
constexpr int AE_BLOCKS = B;                // 48
// Grid: blocks 0..47 AE, blocks 48..3311 MSE chunks.
// ws: [0:4) u32 ticket (memset 0 each replay); bytes 16.. : u64 parts[NCHUNK]
//     part = bitcast(float2{sq_partial, gtsum_partial}), published write-through
//     (agent-scope atomic store, sc0|sc1 -> visible at the coherence point).
// Last MSE block to bump the ticket folds all partials -> out[0]. Each block
// touches the ticket line exactly once (R3's fence storm and R5's polling
// watcher both regressed ~30us; single-touch is the cheap variant).

union PackF2 { unsigned long long u; float2 f; };

__global__ __launch_bounds__(256) void fused_kernel(
        const float* __restrict__ outputs,
        const float* __restrict__ heatmaps,
        const unsigned* __restrict__ joints_u32,
        unsigned* __restrict__ ticket,
        unsigned long long* __restrict__ parts,
        float* __restrict__ out) {
    int t = threadIdx.x;

    if (blockIdx.x >= AE_BLOCKS) {
        // ---- MSE quarter-plane chunk ----
        int chunk = blockIdx.x - AE_BLOCKS;     // 0..3263
        int plane = chunk >> 2, sub = chunk & 3;
        int b = plane / J, j = plane % J;
        const float4* pred = reinterpret_cast<const float4*>(
            outputs + ((size_t)b * 2 * J + j) * HW + sub * CHUNK_FLOATS);
        const float4* gt = reinterpret_cast<const float4*>(
            heatmaps + (size_t)plane * HW + sub * CHUNK_FLOATS);

        float sq = 0.f, gs = 0.f;
#pragma unroll
        for (int k = 0; k < CHUNK_FLOATS / 4 / 256; ++k) {   // 4 iters
            float4 p = pred[t + k * 256];
            float4 g = gt[t + k * 256];
            float d0 = p.x - g.x, d1 = p.y - g.y, d2 = p.z - g.z, d3 = p.w - g.w;
            sq += d0 * d0 + d1 * d1 + d2 * d2 + d3 * d3;
            gs += g.x + g.y + g.z + g.w;
        }
        for (int off = 32; off > 0; off >>= 1) {
            sq += __shfl_xor(sq, off);
            gs += __shfl_xor(gs, off);
        }
        __shared__ float s_sq[4], s_gs[4];
        __shared__ int s_elect;
        int wave = t >> 6;
        if ((t & 63) == 0) { s_sq[wave] = sq; s_gs[wave] = gs; }
        __syncthreads();
        if (t == 0) {
            PackF2 pk;
            pk.f = make_float2(s_sq[0] + s_sq[1] + s_sq[2] + s_sq[3],
                               s_gs[0] + s_gs[1] + s_gs[2] + s_gs[3]);
            // publish write-through to the coherence point (proven in R5)
            __hip_atomic_store(parts + chunk, pk.u, __ATOMIC_RELAXED,
                               __HIP_MEMORY_SCOPE_AGENT);
            // ensure the publication completed before the ticket bump
            asm volatile("s_waitcnt vmcnt(0)" ::: "memory");
            unsigned old = __hip_atomic_fetch_add(ticket, 1u, __ATOMIC_RELAXED,
                                                  __HIP_MEMORY_SCOPE_AGENT);
            s_elect = (old == (unsigned)(NCHUNK - 1)) ? 1 : 0;
        }
        __syncthreads();
        if (s_elect == 0) return;

        // ---- elected last block: fold all partials -> out[0] ----
        float s = 0.f, c = 0.f;
        for (int p = t; p < NPLANES; p += 256) {
            float sqs = 0.f, gss = 0.f;
#pragma unroll
            for (int sub2 = 0; sub2 < SUBS; ++sub2) {
                PackF2 pk;
                pk.u = __hip_atomic_load(parts + p * SUBS + sub2, __ATOMIC_RELAXED,
                                         __HIP_MEMORY_SCOPE_AGENT);
                sqs += pk.f.x; gss += pk.f.y;
            }
            if (gss > 0.f) { s += sqs * (1.f / HW); c += 1.f; }
        }
        for (int off = 32; off > 0; off >>= 1) {
            s += __shfl_xor(s, off);
            c += __shfl_xor(c, off);
        }
        __shared__ float s_s[4], s_c[4];
        if ((t & 63) == 0) { s_s[wave] = s; s_c[wave] = c; }
        __syncthreads();
        if (t == 0) {
            out[0] = (s_s[0] + s_s[1] + s_s[2] + s_s[3]) /
                     (s_c[0] + s_c[1] + s_c[2] + s_c[3]);
        }
        return;
    }

    // ---- AE for batch b (blocks 0..47) ----
    int b = blockIdx.x;
    const float* tags = outputs + ((size_t)b * 2 * J + J) * HW;

    // dtype probe on this batch's joints region (int64-assumed layout):
    // P*J*2 = 1020 int64 values -> odd u32 words all zero iff int64.
    const unsigned* jw = joints_u32 + (size_t)b * P * J * 2 * 2;
    unsigned ob = 0;
#pragma unroll
    for (int k = 0; k < 4; ++k) {
        int i = t + k * 256;
        if (i < P * J * 2) ob |= jw[2 * i + 1];
    }
    __shared__ unsigned s_ob[4];
    for (int off = 32; off > 0; off >>= 1) ob |= (unsigned)__shfl_xor((int)ob, off);
    int wv = t >> 6;
    if ((t & 63) == 0) s_ob[wv] = ob;
    __shared__ float m_sh[P];
    __shared__ int v_sh[P];
    __syncthreads();
    bool is64 = (s_ob[0] | s_ob[1] | s_ob[2] | s_ob[3]) == 0u;

    if (t >= 64) return;
    int lane = t;

    float per_pull = 0.f, m = 0.f;
    int validp = 0;

    if (lane < P) {
        float tv[J];
        int   vv[J];
        int cnt = 0;
        float sum = 0.f;
        if (is64) {
            const long long* jp = reinterpret_cast<const long long*>(joints_u32)
                                  + ((size_t)b * P + lane) * J * 2;
#pragma unroll
            for (int j = 0; j < J; ++j) {
                int idx = (int)jp[2 * j];
                int vis = jp[2 * j + 1] > 0;
                float tval = tags[idx];
                tv[j] = tval; vv[j] = vis;
                cnt += vis;
                sum += vis ? tval : 0.f;
            }
        } else {
            const int* jp = reinterpret_cast<const int*>(joints_u32)
                            + ((size_t)b * P + lane) * J * 2;
#pragma unroll
            for (int j = 0; j < J; ++j) {
                int idx = jp[2 * j];
                int vis = jp[2 * j + 1] > 0;
                float tval = tags[idx];
                tv[j] = tval; vv[j] = vis;
                cnt += vis;
                sum += vis ? tval : 0.f;
            }
        }
        float safe = cnt > 0 ? (float)cnt : 1.f;
        m = sum / safe;
        float pp = 0.f;
#pragma unroll
        for (int j = 0; j < J; ++j) {
            float d = tv[j] - m;
            pp += vv[j] ? d * d : 0.f;
        }
        validp = (cnt > 0) ? 1 : 0;
        per_pull = validp ? pp / safe : 0.f;
        m_sh[lane] = m;
        v_sh[lane] = validp;
    }
    // single wave: drain LDS writes so all lanes see m_sh/v_sh
    __builtin_amdgcn_s_waitcnt(0);

    float push_p = 0.f;
    if (lane < P && validp) {
#pragma unroll
        for (int k = 0; k < P; ++k) {
            if (v_sh[k]) {
                float d = m - m_sh[k];
                push_p += __expf(-d * d);
            }
        }
    }

    float v0 = per_pull, v1 = push_p, v2 = (float)validp;
    for (int off = 32; off > 0; off >>= 1) {
        v0 += __shfl_xor(v0, off);
        v1 += __shfl_xor(v1, off);
        v2 += __shfl_xor(v2, off);
    }
    if (lane == 0) {
        float num_tags = v2;
        float pull = v0 / fmaxf(num_tags, 1.f);
        float push_raw = v1 - num_tags;
        float denom = (num_tags - 1.f) * num_tags;
        float push = (num_tags >= 2.f) ? (push_raw / (denom > 0.f ? denom : 1.f)) * 0.5f : 0.f;
        out[1 + b] = push;
        out[1 + B + b] = pull;
    }
}

extern "C" void kernel_launch(void* const* d_in, const int* in_sizes, int n_in,
                              void* d_out, int out_size, void* d_ws, size_t ws_size,
                              hipStream_t stream) {
    const float* outputs  = (const float*)d_in[0];
    const float* heatmaps = (const float*)d_in[1];
    const unsigned* joints = (const unsigned*)d_in[2];
    float* out = (float*)d_out;
    unsigned* ticket = (unsigned*)d_ws;
    unsigned long long* parts =
        reinterpret_cast<unsigned long long*>((char*)d_ws + 16);

    hipMemsetAsync(d_ws, 0, 4, stream);   // zero ticket each replay
    fused_kernel<<<AE_BLOCKS + NCHUNK, 256, 0, stream>>>(
        outputs, heatmaps, joints, ticket, parts, out);
}

// Round 8
// 48.195 us; speedup vs baseline: 1.2049x; 1.1501x over previous
//
#include <hip/hip_runtime.h>
#include <hip/hip_bf16.h>

// Problem constants
constexpr int B = 48, J = 17, H = 128, W = 128, P = 30;
constexpr int HW = H * W;                   // 16384
constexpr int NPLANES = B * J;              // 816
constexpr int AE_BLOCKS = B;                // 48
// ws (32 B, zeroed by zero_kernel node each call):
//   [byte 0:8)   u64 acc  — fixed-point sum of masked per-plane mse (scale 2^32)
//   [byte 8:12)  u32 cnt  — mask count
//   [byte 12:16) u32 ticket
// Election: each MSE block adds acc/cnt, drains vmcnt, bumps ticket once.
// Block seeing old==NPLANES-1 divides and writes out[0]. No fences, no memset
// node (R3: fence storm = +30us; R5/R6: 4-byte hipMemsetAsync node = ~60us).

__global__ void zero_kernel(unsigned long long* ws64) {
    if (threadIdx.x == 0) { ws64[0] = 0ull; ws64[1] = 0ull; }
}

__global__ __launch_bounds__(256) void fused_kernel(
        const float* __restrict__ outputs,
        const float* __restrict__ heatmaps,
        const unsigned* __restrict__ joints_u32,
        unsigned long long* __restrict__ ws64,
        float* __restrict__ out) {
    int t = threadIdx.x;

    if (blockIdx.x >= AE_BLOCKS) {
        // ---- MSE: one full plane per block ----
        int plane = blockIdx.x - AE_BLOCKS;         // 0..815
        int b = plane / J, j = plane % J;
        const float4* pred = reinterpret_cast<const float4*>(
            outputs + ((size_t)b * 2 * J + j) * HW);
        const float4* gt = reinterpret_cast<const float4*>(
            heatmaps + (size_t)plane * HW);

        float sq = 0.f, gs = 0.f;
#pragma unroll
        for (int k = 0; k < 16; ++k) {
            float4 p = pred[t + k * 256];
            float4 g = gt[t + k * 256];
            float d0 = p.x - g.x, d1 = p.y - g.y, d2 = p.z - g.z, d3 = p.w - g.w;
            sq += d0 * d0 + d1 * d1 + d2 * d2 + d3 * d3;
            gs += g.x + g.y + g.z + g.w;
        }
        for (int off = 32; off > 0; off >>= 1) {
            sq += __shfl_xor(sq, off);
            gs += __shfl_xor(gs, off);
        }
        __shared__ float s_sq[4], s_gs[4];
        int wave = t >> 6;
        if ((t & 63) == 0) { s_sq[wave] = sq; s_gs[wave] = gs; }
        __syncthreads();
        if (t == 0) {
            float tot_sq = s_sq[0] + s_sq[1] + s_sq[2] + s_sq[3];
            float tot_gs = s_gs[0] + s_gs[1] + s_gs[2] + s_gs[3];
            unsigned* ws32 = reinterpret_cast<unsigned*>(ws64);
            if (tot_gs > 0.f) {
                // mse * 2^32 = tot_sq * 2^32 / 16384 = tot_sq * 2^18 (deterministic)
                unsigned long long fx = (unsigned long long)
                    __double2ll_rn((double)tot_sq * 262144.0);
                unsigned long long o1 = __hip_atomic_fetch_add(
                    ws64, fx, __ATOMIC_RELAXED, __HIP_MEMORY_SCOPE_AGENT);
                unsigned o2 = __hip_atomic_fetch_add(
                    ws32 + 2, 1u, __ATOMIC_RELAXED, __HIP_MEMORY_SCOPE_AGENT);
                // keep returns live so the atomics are the returning form,
                // tracked by vmcnt until data comes back from the coherence point
                asm volatile("" :: "v"(o1), "v"(o2));
            }
            // all our adds have completed at the coherence point before the bump
            asm volatile("s_waitcnt vmcnt(0)" ::: "memory");
            unsigned old = __hip_atomic_fetch_add(
                reinterpret_cast<unsigned*>(ws64) + 3, 1u,
                __ATOMIC_RELAXED, __HIP_MEMORY_SCOPE_AGENT);
            if (old == (unsigned)(NPLANES - 1)) {
                // every block's adds precede its ticket bump -> acc/cnt complete
                unsigned long long acc = __hip_atomic_load(
                    ws64, __ATOMIC_RELAXED, __HIP_MEMORY_SCOPE_AGENT);
                unsigned cnt = __hip_atomic_load(
                    reinterpret_cast<unsigned*>(ws64) + 2,
                    __ATOMIC_RELAXED, __HIP_MEMORY_SCOPE_AGENT);
                out[0] = (float)((double)acc * (1.0 / 4294967296.0) / (double)cnt);
            }
        }
        return;
    }

    // ---- AE for batch b (blocks 0..47) ----
    int b = blockIdx.x;
    const float* tags = outputs + ((size_t)b * 2 * J + J) * HW;

    // dtype probe on this batch's joints region (int64-assumed layout):
    // P*J*2 = 1020 int64 values -> odd u32 words all zero iff int64.
    const unsigned* jw = joints_u32 + (size_t)b * P * J * 2 * 2;
    unsigned ob = 0;
#pragma unroll
    for (int k = 0; k < 4; ++k) {
        int i = t + k * 256;
        if (i < P * J * 2) ob |= jw[2 * i + 1];
    }
    __shared__ unsigned s_ob[4];
    for (int off = 32; off > 0; off >>= 1) ob |= (unsigned)__shfl_xor((int)ob, off);
    int wv = t >> 6;
    if ((t & 63) == 0) s_ob[wv] = ob;
    __shared__ float m_sh[P];
    __shared__ int v_sh[P];
    __syncthreads();
    bool is64 = (s_ob[0] | s_ob[1] | s_ob[2] | s_ob[3]) == 0u;

    if (t >= 64) return;
    int lane = t;

    float per_pull = 0.f, m = 0.f;
    int validp = 0;

    if (lane < P) {
        float tv[J];
        int   vv[J];
        int cnt = 0;
        float sum = 0.f;
        if (is64) {
            const long long* jp = reinterpret_cast<const long long*>(joints_u32)
                                  + ((size_t)b * P + lane) * J * 2;
#pragma unroll
            for (int j = 0; j < J; ++j) {
                int idx = (int)jp[2 * j];
                int vis = jp[2 * j + 1] > 0;
                float tval = tags[idx];
                tv[j] = tval; vv[j] = vis;
                cnt += vis;
                sum += vis ? tval : 0.f;
            }
        } else {
            const int* jp = reinterpret_cast<const int*>(joints_u32)
                            + ((size_t)b * P + lane) * J * 2;
#pragma unroll
            for (int j = 0; j < J; ++j) {
                int idx = jp[2 * j];
                int vis = jp[2 * j + 1] > 0;
                float tval = tags[idx];
                tv[j] = tval; vv[j] = vis;
                cnt += vis;
                sum += vis ? tval : 0.f;
            }
        }
        float safe = cnt > 0 ? (float)cnt : 1.f;
        m = sum / safe;
        float pp = 0.f;
#pragma unroll
        for (int j = 0; j < J; ++j) {
            float d = tv[j] - m;
            pp += vv[j] ? d * d : 0.f;
        }
        validp = (cnt > 0) ? 1 : 0;
        per_pull = validp ? pp / safe : 0.f;
        m_sh[lane] = m;
        v_sh[lane] = validp;
    }
    // single wave: drain LDS writes so all lanes see m_sh/v_sh
    __builtin_amdgcn_s_waitcnt(0);

    float push_p = 0.f;
    if (lane < P && validp) {
#pragma unroll
        for (int k = 0; k < P; ++k) {
            if (v_sh[k]) {
                float d = m - m_sh[k];
                push_p += __expf(-d * d);
            }
        }
    }

    float v0 = per_pull, v1 = push_p, v2 = (float)validp;
    for (int off = 32; off > 0; off >>= 1) {
        v0 += __shfl_xor(v0, off);
        v1 += __shfl_xor(v1, off);
        v2 += __shfl_xor(v2, off);
    }
    if (lane == 0) {
        float num_tags = v2;
        float pull = v0 / fmaxf(num_tags, 1.f);
        float push_raw = v1 - num_tags;
        float denom = (num_tags - 1.f) * num_tags;
        float push = (num_tags >= 2.f) ? (push_raw / (denom > 0.f ? denom : 1.f)) * 0.5f : 0.f;
        out[1 + b] = push;
        out[1 + B + b] = pull;
    }
}

extern "C" void kernel_launch(void* const* d_in, const int* in_sizes, int n_in,
                              void* d_out, int out_size, void* d_ws, size_t ws_size,
                              hipStream_t stream) {
    const float* outputs  = (const float*)d_in[0];
    const float* heatmaps = (const float*)d_in[1];
    const unsigned* joints = (const unsigned*)d_in[2];
    float* out = (float*)d_out;
    unsigned long long* ws64 = (unsigned long long*)d_ws;

    zero_kernel<<<1, 64, 0, stream>>>(ws64);   // reset acc/cnt/ticket (NOT hipMemsetAsync)
    fused_kernel<<<AE_BLOCKS + NPLANES, 256, 0, stream>>>(
        outputs, heatmaps, joints, ws64, out);
}

// Round 9
// 30.116 us; speedup vs baseline: 1.9282x; 1.6003x over previous
//
#include <hip/hip_runtime.h>
#include <hip/hip_bf16.h>

// Problem constants
constexpr int B = 48, J = 17, H = 128, W = 128, P = 30;
constexpr int HW = H * W;                   // 16384
constexpr int NPLANES = B * J;              // 816
constexpr int SUBS = 4;                     // quarter-planes
constexpr int CHUNK_FLOATS = HW / SUBS;     // 4096
constexpr int NCHUNK = NPLANES * SUBS;      // 3264
constexpr int AE_BLOCKS = B;                // 48
constexpr int GROUPS = 64;                  // 3264 = 64 * 51 exactly
constexpr int GROUP_SZ = NCHUNK / GROUPS;   // 51
// ws layout:
//   u64 parts[NCHUNK]                      bytes [0, 26112)   (rewritten every call)
//   u32 group_arrivals[64] @128B stride    bytes [26112, 34304)
//   u32 global_arrivals    @ byte 34304
// Hierarchy keeps same-line RMW counts <= 64 (R6/R8 showed ~10-18ns per
// serialized same-line RMW: 1632-2448 on one line cost +24-30us).
constexpr int PART_U32 = NCHUNK * 2;        // 6528
constexpr int GROUP_ARR_U32 = PART_U32;     // ws_u32 index of group 0 arrival
constexpr int GLOBAL_ARR_U32 = PART_U32 + GROUPS * 32;  // 8576

union PackF2 { unsigned long long u; float2 f; };

__global__ void zero_kernel(unsigned* ws_u32) {
    int t = threadIdx.x;
    if (t < GROUPS) ws_u32[GROUP_ARR_U32 + t * 32] = 0u;
    if (t == GROUPS) ws_u32[GLOBAL_ARR_U32] = 0u;
}

__global__ __launch_bounds__(256) void fused_kernel(
        const float* __restrict__ outputs,
        const float* __restrict__ heatmaps,
        const unsigned* __restrict__ joints_u32,
        unsigned long long* __restrict__ parts,
        unsigned* __restrict__ ws_u32,
        float* __restrict__ out) {
    int t = threadIdx.x;

    if (blockIdx.x < NCHUNK) {
        // ---- MSE quarter-plane chunk ----
        int chunk = blockIdx.x;                 // 0..3263
        int plane = chunk >> 2, sub = chunk & 3;
        int b = plane / J, j = plane % J;
        const float4* pred = reinterpret_cast<const float4*>(
            outputs + ((size_t)b * 2 * J + j) * HW + sub * CHUNK_FLOATS);
        const float4* gt = reinterpret_cast<const float4*>(
            heatmaps + (size_t)plane * HW + sub * CHUNK_FLOATS);

        float sq = 0.f, gs = 0.f;
#pragma unroll
        for (int k = 0; k < CHUNK_FLOATS / 4 / 256; ++k) {   // 4 iters
            float4 p = pred[t + k * 256];
            float4 g = gt[t + k * 256];
            float d0 = p.x - g.x, d1 = p.y - g.y, d2 = p.z - g.z, d3 = p.w - g.w;
            sq += d0 * d0 + d1 * d1 + d2 * d2 + d3 * d3;
            gs += g.x + g.y + g.z + g.w;
        }
        for (int off = 32; off > 0; off >>= 1) {
            sq += __shfl_xor(sq, off);
            gs += __shfl_xor(gs, off);
        }
        __shared__ float s_sq[4], s_gs[4];
        __shared__ int s_elect;
        int wave = t >> 6;
        if ((t & 63) == 0) { s_sq[wave] = sq; s_gs[wave] = gs; }
        __syncthreads();
        if (t == 0) {
            int elect = 0;
            PackF2 pk;
            pk.f = make_float2(s_sq[0] + s_sq[1] + s_sq[2] + s_sq[3],
                               s_gs[0] + s_gs[1] + s_gs[2] + s_gs[3]);
            // publish with RETURNING exchange -> vmcnt-tracked until data
            // returns from the coherence point (completion guarantee)
            unsigned long long oldp = __hip_atomic_exchange(
                parts + chunk, pk.u, __ATOMIC_RELAXED, __HIP_MEMORY_SCOPE_AGENT);
            asm volatile("" :: "v"(oldp));
            asm volatile("s_waitcnt vmcnt(0)" ::: "memory");
            // group arrival (51 RMWs per 128B line, 64 lines in parallel)
            int g = chunk / GROUP_SZ;
            unsigned ga = __hip_atomic_fetch_add(
                ws_u32 + GROUP_ARR_U32 + g * 32, 1u,
                __ATOMIC_RELAXED, __HIP_MEMORY_SCOPE_AGENT);
            if (ga == (unsigned)(GROUP_SZ - 1)) {
                // group-last: all 51 publishes of this group are complete
                unsigned gl = __hip_atomic_fetch_add(
                    ws_u32 + GLOBAL_ARR_U32, 1u,
                    __ATOMIC_RELAXED, __HIP_MEMORY_SCOPE_AGENT);
                elect = (gl == (unsigned)(GROUPS - 1)) ? 1 : 0;
            }
            s_elect = elect;
        }
        __syncthreads();
        if (s_elect == 0) return;

        // ---- elected global-last block: exact per-plane masked fold ----
        float s = 0.f, c = 0.f;
        for (int p = t; p < NPLANES; p += 256) {
            float sqs = 0.f, gss = 0.f;
#pragma unroll
            for (int sub2 = 0; sub2 < SUBS; ++sub2) {
                PackF2 pk;
                pk.u = __hip_atomic_load(parts + p * SUBS + sub2, __ATOMIC_RELAXED,
                                         __HIP_MEMORY_SCOPE_AGENT);
                sqs += pk.f.x; gss += pk.f.y;
            }
            if (gss > 0.f) { s += sqs * (1.f / HW); c += 1.f; }
        }
        for (int off = 32; off > 0; off >>= 1) {
            s += __shfl_xor(s, off);
            c += __shfl_xor(c, off);
        }
        __shared__ float s_s[4], s_c[4];
        if ((t & 63) == 0) { s_s[wave] = s; s_c[wave] = c; }
        __syncthreads();
        if (t == 0) {
            out[0] = (s_s[0] + s_s[1] + s_s[2] + s_s[3]) /
                     (s_c[0] + s_c[1] + s_c[2] + s_c[3]);
        }
        return;
    }

    // ---- AE for batch b (blocks 3264..3311) ----
    int b = blockIdx.x - NCHUNK;
    const float* tags = outputs + ((size_t)b * 2 * J + J) * HW;

    // dtype probe on this batch's joints region (int64-assumed layout):
    // P*J*2 = 1020 int64 values -> odd u32 words all zero iff int64.
    const unsigned* jw = joints_u32 + (size_t)b * P * J * 2 * 2;
    unsigned ob = 0;
#pragma unroll
    for (int k = 0; k < 4; ++k) {
        int i = t + k * 256;
        if (i < P * J * 2) ob |= jw[2 * i + 1];
    }
    __shared__ unsigned s_ob[4];
    for (int off = 32; off > 0; off >>= 1) ob |= (unsigned)__shfl_xor((int)ob, off);
    int wv = t >> 6;
    if ((t & 63) == 0) s_ob[wv] = ob;
    __shared__ float m_sh[P];
    __shared__ int v_sh[P];
    __syncthreads();
    bool is64 = (s_ob[0] | s_ob[1] | s_ob[2] | s_ob[3]) == 0u;

    if (t >= 64) return;
    int lane = t;

    float per_pull = 0.f, m = 0.f;
    int validp = 0;

    if (lane < P) {
        float tv[J];
        int   vv[J];
        int cnt = 0;
        float sum = 0.f;
        if (is64) {
            const long long* jp = reinterpret_cast<const long long*>(joints_u32)
                                  + ((size_t)b * P + lane) * J * 2;
#pragma unroll
            for (int j = 0; j < J; ++j) {
                int idx = (int)jp[2 * j];
                int vis = jp[2 * j + 1] > 0;
                float tval = tags[idx];
                tv[j] = tval; vv[j] = vis;
                cnt += vis;
                sum += vis ? tval : 0.f;
            }
        } else {
            const int* jp = reinterpret_cast<const int*>(joints_u32)
                            + ((size_t)b * P + lane) * J * 2;
#pragma unroll
            for (int j = 0; j < J; ++j) {
                int idx = jp[2 * j];
                int vis = jp[2 * j + 1] > 0;
                float tval = tags[idx];
                tv[j] = tval; vv[j] = vis;
                cnt += vis;
                sum += vis ? tval : 0.f;
            }
        }
        float safe = cnt > 0 ? (float)cnt : 1.f;
        m = sum / safe;
        float pp = 0.f;
#pragma unroll
        for (int j = 0; j < J; ++j) {
            float d = tv[j] - m;
            pp += vv[j] ? d * d : 0.f;
        }
        validp = (cnt > 0) ? 1 : 0;
        per_pull = validp ? pp / safe : 0.f;
        m_sh[lane] = m;
        v_sh[lane] = validp;
    }
    // single wave: drain LDS writes so all lanes see m_sh/v_sh
    __builtin_amdgcn_s_waitcnt(0);

    float push_p = 0.f;
    if (lane < P && validp) {
#pragma unroll
        for (int k = 0; k < P; ++k) {
            if (v_sh[k]) {
                float d = m - m_sh[k];
                push_p += __expf(-d * d);
            }
        }
    }

    float v0 = per_pull, v1 = push_p, v2 = (float)validp;
    for (int off = 32; off > 0; off >>= 1) {
        v0 += __shfl_xor(v0, off);
        v1 += __shfl_xor(v1, off);
        v2 += __shfl_xor(v2, off);
    }
    if (lane == 0) {
        float num_tags = v2;
        float pull = v0 / fmaxf(num_tags, 1.f);
        float push_raw = v1 - num_tags;
        float denom = (num_tags - 1.f) * num_tags;
        float push = (num_tags >= 2.f) ? (push_raw / (denom > 0.f ? denom : 1.f)) * 0.5f : 0.f;
        out[1 + b] = push;
        out[1 + B + b] = pull;
    }
}

extern "C" void kernel_launch(void* const* d_in, const int* in_sizes, int n_in,
                              void* d_out, int out_size, void* d_ws, size_t ws_size,
                              hipStream_t stream) {
    const float* outputs  = (const float*)d_in[0];
    const float* heatmaps = (const float*)d_in[1];
    const unsigned* joints = (const unsigned*)d_in[2];
    float* out = (float*)d_out;
    unsigned long long* parts = (unsigned long long*)d_ws;
    unsigned* ws_u32 = (unsigned*)d_ws;

    zero_kernel<<<1, 128, 0, stream>>>(ws_u32);   // reset 65 arrival words
    fused_kernel<<<NCHUNK + AE_BLOCKS, 256, 0, stream>>>(
        outputs, heatmaps, joints, parts, ws_u32, out);
}

// Round 11
// 25.112 us; speedup vs baseline: 2.3125x; 1.1993x over previous
//
#include <hip/hip_runtime.h>
#include <hip/hip_bf16.h>

// Problem constants
constexpr int B = 48, J = 17, H = 128, W = 128, P = 30;
constexpr int HW = H * W;                   // 16384
constexpr int NPLANES = B * J;              // 816
constexpr int SUBS = 4;                     // quarter-planes
constexpr int CHUNK_FLOATS = HW / SUBS;     // 4096
constexpr int NCHUNK = NPLANES * SUBS;      // 3264
constexpr int AE_BLOCKS = B;                // 48
// ws: float2 parts[NCHUNK]; parts[plane*SUBS+sub] = {sq_partial, gtsum_partial}
// Two launches (R3/R5/R6/R8/R9: all single-launch sync schemes cost >= +6us):
//   1) mse_kernel: 3264 uniform streaming blocks
//   2) tail_kernel: 48 AE blocks + 1 finalize block (overlapped)

typedef float f32x4 __attribute__((ext_vector_type(4)));

__global__ __launch_bounds__(256) void mse_kernel(
        const float* __restrict__ outputs,
        const float* __restrict__ heatmaps,
        float2* __restrict__ parts) {
    int t = threadIdx.x;
    int chunk = blockIdx.x;                 // 0..3263
    int plane = chunk >> 2, sub = chunk & 3;
    int b = plane / J, j = plane % J;
    const f32x4* pred = reinterpret_cast<const f32x4*>(
        outputs + ((size_t)b * 2 * J + j) * HW + sub * CHUNK_FLOATS);
    const f32x4* gt = reinterpret_cast<const f32x4*>(
        heatmaps + (size_t)plane * HW + sub * CHUNK_FLOATS);

    float sq = 0.f, gs = 0.f;
#pragma unroll
    for (int k = 0; k < CHUNK_FLOATS / 4 / 256; ++k) {   // 4 iters
        f32x4 p = __builtin_nontemporal_load(&pred[t + k * 256]);
        f32x4 g = __builtin_nontemporal_load(&gt[t + k * 256]);
        float d0 = p.x - g.x, d1 = p.y - g.y, d2 = p.z - g.z, d3 = p.w - g.w;
        sq += d0 * d0 + d1 * d1 + d2 * d2 + d3 * d3;
        gs += g.x + g.y + g.z + g.w;
    }
    for (int off = 32; off > 0; off >>= 1) {
        sq += __shfl_xor(sq, off);
        gs += __shfl_xor(gs, off);
    }
    __shared__ float s_sq[4], s_gs[4];
    int wave = t >> 6;
    if ((t & 63) == 0) { s_sq[wave] = sq; s_gs[wave] = gs; }
    __syncthreads();
    if (t == 0) {
        parts[chunk] = make_float2(s_sq[0] + s_sq[1] + s_sq[2] + s_sq[3],
                                   s_gs[0] + s_gs[1] + s_gs[2] + s_gs[3]);
    }
}

// blocks 0..47: AE per batch; block 48: fold MSE partials -> out[0]
__global__ __launch_bounds__(256) void tail_kernel(
        const float* __restrict__ outputs,
        const unsigned* __restrict__ joints_u32,
        const float2* __restrict__ parts,
        float* __restrict__ out) {
    int t = threadIdx.x;

    if (blockIdx.x == AE_BLOCKS) {
        // ---- finalize fold ----
        float s = 0.f, c = 0.f;
        for (int p = t; p < NPLANES; p += 256) {
            float sq = 0.f, gs = 0.f;
#pragma unroll
            for (int sub = 0; sub < SUBS; ++sub) {
                float2 v = parts[p * SUBS + sub];
                sq += v.x; gs += v.y;
            }
            if (gs > 0.f) { s += sq * (1.f / HW); c += 1.f; }
        }
        for (int off = 32; off > 0; off >>= 1) {
            s += __shfl_xor(s, off);
            c += __shfl_xor(c, off);
        }
        __shared__ float s_s[4], s_c[4];
        int wave = t >> 6;
        if ((t & 63) == 0) { s_s[wave] = s; s_c[wave] = c; }
        __syncthreads();
        if (t == 0) {
            out[0] = (s_s[0] + s_s[1] + s_s[2] + s_s[3]) /
                     (s_c[0] + s_c[1] + s_c[2] + s_c[3]);
        }
        return;
    }

    // ---- AE for batch b ----
    int b = blockIdx.x;
    const float* tags = outputs + ((size_t)b * 2 * J + J) * HW;

    // dtype probe on this batch's joints region (int64-assumed layout):
    // P*J*2 = 1020 int64 values -> odd u32 words all zero iff int64.
    const unsigned* jw = joints_u32 + (size_t)b * P * J * 2 * 2;
    unsigned ob = 0;
#pragma unroll
    for (int k = 0; k < 4; ++k) {
        int i = t + k * 256;
        if (i < P * J * 2) ob |= jw[2 * i + 1];
    }
    __shared__ unsigned s_ob[4];
    for (int off = 32; off > 0; off >>= 1) ob |= (unsigned)__shfl_xor((int)ob, off);
    int wv = t >> 6;
    if ((t & 63) == 0) s_ob[wv] = ob;
    __shared__ float m_sh[P];
    __shared__ int v_sh[P];
    __syncthreads();
    bool is64 = (s_ob[0] | s_ob[1] | s_ob[2] | s_ob[3]) == 0u;

    if (t >= 64) return;
    int lane = t;

    float per_pull = 0.f, m = 0.f;
    int validp = 0;

    if (lane < P) {
        float tv[J];
        int   vv[J];
        int cnt = 0;
        float sum = 0.f;
        if (is64) {
            const long long* jp = reinterpret_cast<const long long*>(joints_u32)
                                  + ((size_t)b * P + lane) * J * 2;
#pragma unroll
            for (int j = 0; j < J; ++j) {
                int idx = (int)jp[2 * j];
                int vis = jp[2 * j + 1] > 0;
                float tval = tags[idx];
                tv[j] = tval; vv[j] = vis;
                cnt += vis;
                sum += vis ? tval : 0.f;
            }
        } else {
            const int* jp = reinterpret_cast<const int*>(joints_u32)
                            + ((size_t)b * P + lane) * J * 2;
#pragma unroll
            for (int j = 0; j < J; ++j) {
                int idx = jp[2 * j];
                int vis = jp[2 * j + 1] > 0;
                float tval = tags[idx];
                tv[j] = tval; vv[j] = vis;
                cnt += vis;
                sum += vis ? tval : 0.f;
            }
        }
        float safe = cnt > 0 ? (float)cnt : 1.f;
        m = sum / safe;
        float pp = 0.f;
#pragma unroll
        for (int j = 0; j < J; ++j) {
            float d = tv[j] - m;
            pp += vv[j] ? d * d : 0.f;
        }
        validp = (cnt > 0) ? 1 : 0;
        per_pull = validp ? pp / safe : 0.f;
        m_sh[lane] = m;
        v_sh[lane] = validp;
    }
    // single wave: drain LDS writes so all lanes see m_sh/v_sh
    __builtin_amdgcn_s_waitcnt(0);

    float push_p = 0.f;
    if (lane < P && validp) {
#pragma unroll
        for (int k = 0; k < P; ++k) {
            if (v_sh[k]) {
                float d = m - m_sh[k];
                push_p += __expf(-d * d);
            }
        }
    }

    float v0 = per_pull, v1 = push_p, v2 = (float)validp;
    for (int off = 32; off > 0; off >>= 1) {
        v0 += __shfl_xor(v0, off);
        v1 += __shfl_xor(v1, off);
        v2 += __shfl_xor(v2, off);
    }
    if (lane == 0) {
        float num_tags = v2;
        float pull = v0 / fmaxf(num_tags, 1.f);
        float push_raw = v1 - num_tags;
        float denom = (num_tags - 1.f) * num_tags;
        float push = (num_tags >= 2.f) ? (push_raw / (denom > 0.f ? denom : 1.f)) * 0.5f : 0.f;
        out[1 + b] = push;
        out[1 + B + b] = pull;
    }
}

extern "C" void kernel_launch(void* const* d_in, const int* in_sizes, int n_in,
                              void* d_out, int out_size, void* d_ws, size_t ws_size,
                              hipStream_t stream) {
    const float* outputs  = (const float*)d_in[0];
    const float* heatmaps = (const float*)d_in[1];
    const unsigned* joints = (const unsigned*)d_in[2];
    float* out = (float*)d_out;
    float2* parts = (float2*)d_ws;

    mse_kernel<<<NCHUNK, 256, 0, stream>>>(outputs, heatmaps, parts);
    tail_kernel<<<AE_BLOCKS + 1, 256, 0, stream>>>(outputs, joints, parts, out);
}

// Round 12
// 24.353 us; speedup vs baseline: 2.3845x; 1.0311x over previous
//
#include <hip/hip_runtime.h>
#include <hip/hip_bf16.h>

// Problem constants
constexpr int B = 48, J = 17, H = 128, W = 128, P = 30;
constexpr int HW = H * W;                   // 16384
constexpr int NPLANES = B * J;              // 816
constexpr int SUBS = 8;                     // eighth-planes
constexpr int CHUNK_FLOATS = HW / SUBS;     // 2048
constexpr int NCHUNK = NPLANES * SUBS;      // 6528
constexpr int AE_BLOCKS = B;                // 48
// ws: float2 parts[NCHUNK]; parts[plane*SUBS+sub] = {sq_partial, gtsum_partial}
// Structure = R4 (best measured: 24.2us): kernel1 = AE + MSE chunks,
// kernel2 = 1-block fold. R3/R5/R6/R8/R9: single-launch sync >= +6us.
// R11: nontemporal loads forfeit L3 residency -> regular loads here.

__global__ __launch_bounds__(256) void fused_kernel(
        const float* __restrict__ outputs,
        const float* __restrict__ heatmaps,
        const unsigned* __restrict__ joints_u32,
        float2* __restrict__ parts,
        float* __restrict__ out) {
    int t = threadIdx.x;

    if (blockIdx.x >= AE_BLOCKS) {
        // ---- MSE eighth-plane chunk ----
        int chunk = blockIdx.x - AE_BLOCKS;     // 0..6527
        int plane = chunk >> 3, sub = chunk & 7;
        int b = plane / J, j = plane % J;
        const float4* pred = reinterpret_cast<const float4*>(
            outputs + ((size_t)b * 2 * J + j) * HW + sub * CHUNK_FLOATS);
        const float4* gt = reinterpret_cast<const float4*>(
            heatmaps + (size_t)plane * HW + sub * CHUNK_FLOATS);

        float sq = 0.f, gs = 0.f;
#pragma unroll
        for (int k = 0; k < CHUNK_FLOATS / 4 / 256; ++k) {   // 2 iters
            float4 p = pred[t + k * 256];
            float4 g = gt[t + k * 256];
            float d0 = p.x - g.x, d1 = p.y - g.y, d2 = p.z - g.z, d3 = p.w - g.w;
            sq += d0 * d0 + d1 * d1 + d2 * d2 + d3 * d3;
            gs += g.x + g.y + g.z + g.w;
        }
        for (int off = 32; off > 0; off >>= 1) {
            sq += __shfl_xor(sq, off);
            gs += __shfl_xor(gs, off);
        }
        __shared__ float s_sq[4], s_gs[4];
        int wave = t >> 6;
        if ((t & 63) == 0) { s_sq[wave] = sq; s_gs[wave] = gs; }
        __syncthreads();
        if (t == 0) {
            parts[chunk] = make_float2(s_sq[0] + s_sq[1] + s_sq[2] + s_sq[3],
                                       s_gs[0] + s_gs[1] + s_gs[2] + s_gs[3]);
        }
        return;
    }

    // ---- AE for batch b (blocks 0..47) ----
    int b = blockIdx.x;
    const float* tags = outputs + ((size_t)b * 2 * J + J) * HW;

    // dtype probe on this batch's joints region (int64-assumed layout):
    // P*J*2 = 1020 int64 values -> odd u32 words all zero iff int64.
    const unsigned* jw = joints_u32 + (size_t)b * P * J * 2 * 2;
    unsigned ob = 0;
#pragma unroll
    for (int k = 0; k < 4; ++k) {
        int i = t + k * 256;
        if (i < P * J * 2) ob |= jw[2 * i + 1];
    }
    __shared__ unsigned s_ob[4];
    for (int off = 32; off > 0; off >>= 1) ob |= (unsigned)__shfl_xor((int)ob, off);
    int wv = t >> 6;
    if ((t & 63) == 0) s_ob[wv] = ob;
    __shared__ float m_sh[P];
    __shared__ int v_sh[P];
    __syncthreads();
    bool is64 = (s_ob[0] | s_ob[1] | s_ob[2] | s_ob[3]) == 0u;

    if (t >= 64) return;
    int lane = t;

    float per_pull = 0.f, m = 0.f;
    int validp = 0;

    if (lane < P) {
        float tv[J];
        int   vv[J];
        int cnt = 0;
        float sum = 0.f;
        if (is64) {
            const long long* jp = reinterpret_cast<const long long*>(joints_u32)
                                  + ((size_t)b * P + lane) * J * 2;
#pragma unroll
            for (int j = 0; j < J; ++j) {
                int idx = (int)jp[2 * j];
                int vis = jp[2 * j + 1] > 0;
                float tval = tags[idx];
                tv[j] = tval; vv[j] = vis;
                cnt += vis;
                sum += vis ? tval : 0.f;
            }
        } else {
            const int* jp = reinterpret_cast<const int*>(joints_u32)
                            + ((size_t)b * P + lane) * J * 2;
#pragma unroll
            for (int j = 0; j < J; ++j) {
                int idx = jp[2 * j];
                int vis = jp[2 * j + 1] > 0;
                float tval = tags[idx];
                tv[j] = tval; vv[j] = vis;
                cnt += vis;
                sum += vis ? tval : 0.f;
            }
        }
        float safe = cnt > 0 ? (float)cnt : 1.f;
        m = sum / safe;
        float pp = 0.f;
#pragma unroll
        for (int j = 0; j < J; ++j) {
            float d = tv[j] - m;
            pp += vv[j] ? d * d : 0.f;
        }
        validp = (cnt > 0) ? 1 : 0;
        per_pull = validp ? pp / safe : 0.f;
        m_sh[lane] = m;
        v_sh[lane] = validp;
    }
    // single wave: drain LDS writes so all lanes see m_sh/v_sh
    __builtin_amdgcn_s_waitcnt(0);

    float push_p = 0.f;
    if (lane < P && validp) {
#pragma unroll
        for (int k = 0; k < P; ++k) {
            if (v_sh[k]) {
                float d = m - m_sh[k];
                push_p += __expf(-d * d);
            }
        }
    }

    float v0 = per_pull, v1 = push_p, v2 = (float)validp;
    for (int off = 32; off > 0; off >>= 1) {
        v0 += __shfl_xor(v0, off);
        v1 += __shfl_xor(v1, off);
        v2 += __shfl_xor(v2, off);
    }
    if (lane == 0) {
        float num_tags = v2;
        float pull = v0 / fmaxf(num_tags, 1.f);
        float push_raw = v1 - num_tags;
        float denom = (num_tags - 1.f) * num_tags;
        float push = (num_tags >= 2.f) ? (push_raw / (denom > 0.f ? denom : 1.f)) * 0.5f : 0.f;
        out[1 + b] = push;
        out[1 + B + b] = pull;
    }
}

// ---------------- Kernel B: fold per-chunk partials -> out[0] ----------------
__global__ __launch_bounds__(256) void finalize_kernel(const float2* __restrict__ parts,
                                                       float* __restrict__ out) {
    int t = threadIdx.x;
    float s = 0.f, c = 0.f;
    for (int p = t; p < NPLANES; p += 256) {
        float sq = 0.f, gs = 0.f;
#pragma unroll
        for (int sub = 0; sub < SUBS; ++sub) {
            float2 v = parts[p * SUBS + sub];
            sq += v.x; gs += v.y;
        }
        bool mask = gs > 0.f;
        s += mask ? sq * (1.f / HW) : 0.f;
        c += mask ? 1.f : 0.f;
    }
    for (int off = 32; off > 0; off >>= 1) {
        s += __shfl_xor(s, off);
        c += __shfl_xor(c, off);
    }
    __shared__ float s_s[4], s_c[4];
    int wave = t >> 6;
    if ((t & 63) == 0) { s_s[wave] = s; s_c[wave] = c; }
    __syncthreads();
    if (t == 0) {
        out[0] = (s_s[0] + s_s[1] + s_s[2] + s_s[3]) /
                 (s_c[0] + s_c[1] + s_c[2] + s_c[3]);
    }
}

extern "C" void kernel_launch(void* const* d_in, const int* in_sizes, int n_in,
                              void* d_out, int out_size, void* d_ws, size_t ws_size,
                              hipStream_t stream) {
    const float* outputs  = (const float*)d_in[0];
    const float* heatmaps = (const float*)d_in[1];
    const unsigned* joints = (const unsigned*)d_in[2];
    float* out = (float*)d_out;
    float2* parts = (float2*)d_ws;

    fused_kernel<<<AE_BLOCKS + NCHUNK, 256, 0, stream>>>(
        outputs, heatmaps, joints, parts, out);
    finalize_kernel<<<1, 256, 0, stream>>>(parts, out);
}